// Round 1
// baseline (498.479 us; speedup 1.0000x reference)
//
#include <hip/hip_runtime.h>
#include <hip/hip_bf16.h>

// Problem constants
#define B_  2
#define N_  2048
#define DM_ 512
#define H_  8
#define DK_ 64
#define DV_ 64
#define BN_ (B_*N_)   // 4096 tokens

// ---------------------------------------------------------------------------
// Kernel 1: fuse base + lora weights/biases
// ---------------------------------------------------------------------------
__global__ void fuse_wb(const float* __restrict__ Wq, const float* __restrict__ WqL,
                        const float* __restrict__ Wk, const float* __restrict__ WkL,
                        const float* __restrict__ Wv, const float* __restrict__ WvL,
                        const float* __restrict__ bq, const float* __restrict__ bqL,
                        const float* __restrict__ bk, const float* __restrict__ bkL,
                        const float* __restrict__ bv, const float* __restrict__ bvL,
                        float* __restrict__ Wf, float* __restrict__ bf) {
    int idx = blockIdx.x * blockDim.x + threadIdx.x;
    const int per = DM_ * DM_;           // 262144
    if (idx < 3 * per) {
        int w = idx / per, i = idx % per;
        const float* a = (w == 0) ? Wq : (w == 1) ? Wk : Wv;
        const float* b = (w == 0) ? WqL : (w == 1) ? WkL : WvL;
        Wf[idx] = a[i] + b[i];
    }
    if (idx < 3 * DM_) {
        int w = idx / DM_, i = idx % DM_;
        const float* a = (w == 0) ? bq : (w == 1) ? bk : bv;
        const float* b = (w == 0) ? bqL : (w == 1) ? bkL : bvL;
        bf[idx] = a[i] + b[i];
    }
}

// ---------------------------------------------------------------------------
// Kernel 2: QKV GEMM  [4096,512] @ [512,512] (+bias), z = {q,k,v}
// writes output in [B,H,N,64] layout
// ---------------------------------------------------------------------------
__global__ __launch_bounds__(256) void qkv_gemm(const float* __restrict__ x,
                                                const float* __restrict__ Wf,
                                                const float* __restrict__ bf,
                                                float* __restrict__ Qd,
                                                float* __restrict__ Kd,
                                                float* __restrict__ Vd) {
    const int w  = blockIdx.z;
    const float* Wp = Wf + (size_t)w * DM_ * DM_;
    float* out = (w == 0) ? Qd : (w == 1) ? Kd : Vd;
    const int rt = blockIdx.x;   // token-row tile (64 rows)
    const int ct = blockIdx.y;   // col tile (64 cols) == head index

    __shared__ float As[64][33];   // padded: conflict-free
    __shared__ float Bs[32][68];   // padded, 16B-aligned rows

    const int t  = threadIdx.x;
    const int tx = t & 15, ty = t >> 4;

    float acc[4][4] = {};

    for (int k0 = 0; k0 < DM_; k0 += 32) {
#pragma unroll
        for (int i = 0; i < 2; i++) {
            int e = (t + i * 256) * 4;            // element id in 64x32 tile
            int r = e >> 5, c = e & 31;
            float4 v = *reinterpret_cast<const float4*>(
                x + (size_t)(rt * 64 + r) * DM_ + k0 + c);
            As[r][c] = v.x; As[r][c + 1] = v.y; As[r][c + 2] = v.z; As[r][c + 3] = v.w;
        }
#pragma unroll
        for (int i = 0; i < 2; i++) {
            int e = (t + i * 256) * 4;            // element id in 32x64 tile
            int r = e >> 6, c = e & 63;
            float4 v = *reinterpret_cast<const float4*>(
                Wp + (size_t)(k0 + r) * DM_ + ct * 64 + c);
            Bs[r][c] = v.x; Bs[r][c + 1] = v.y; Bs[r][c + 2] = v.z; Bs[r][c + 3] = v.w;
        }
        __syncthreads();
#pragma unroll
        for (int kk = 0; kk < 32; kk++) {
            float a[4], b[4];
#pragma unroll
            for (int i = 0; i < 4; i++) a[i] = As[ty * 4 + i][kk];
#pragma unroll
            for (int j = 0; j < 4; j++) b[j] = Bs[kk][tx * 4 + j];
#pragma unroll
            for (int i = 0; i < 4; i++)
#pragma unroll
                for (int j = 0; j < 4; j++) acc[i][j] += a[i] * b[j];
        }
        __syncthreads();
    }

    // epilogue: bias + store to [B,H,N,64]
#pragma unroll
    for (int i = 0; i < 4; i++) {
        int row = rt * 64 + ty * 4 + i;       // global token id 0..4095
        int b = row >> 11, n = row & (N_ - 1);
#pragma unroll
        for (int j = 0; j < 4; j++) {
            int d = tx * 4 + j;
            float val = acc[i][j] + bf[w * DM_ + ct * 64 + d];
            out[(((size_t)(b * H_ + ct) * N_ + n)) * DK_ + d] = val;
        }
    }
}

// ---------------------------------------------------------------------------
// Kernel 3: flash attention.  grid = (N/64, B*H), block = 256
// Q,K,V in [B,H,N,64]; output written in [B,N,H*64] layout
// ---------------------------------------------------------------------------
__global__ __launch_bounds__(256) void attn_fwd(const float* __restrict__ Q,
                                                const float* __restrict__ K,
                                                const float* __restrict__ V,
                                                float* __restrict__ O) {
    const int bh = blockIdx.y;
    const int qt = blockIdx.x;
    const float* Qp = Q + ((size_t)bh * N_ + qt * 64) * DK_;
    const float* Kp = K + (size_t)bh * N_ * DK_;
    const float* Vp = V + (size_t)bh * N_ * DK_;

    __shared__ float Qs[64][65], Ks[64][65], Vs[64][65], Ps[64][65];

    const int t  = threadIdx.x;
    const int tx = t & 15, ty = t >> 4;

    // load Q tile once
#pragma unroll
    for (int i = 0; i < 4; i++) {
        int e = (t + i * 256) * 4; int r = e >> 6, c = e & 63;
        float4 v = *reinterpret_cast<const float4*>(Qp + (size_t)r * DK_ + c);
        Qs[r][c] = v.x; Qs[r][c + 1] = v.y; Qs[r][c + 2] = v.z; Qs[r][c + 3] = v.w;
    }

    float m[4], l[4], o[4][4] = {};
#pragma unroll
    for (int i = 0; i < 4; i++) { m[i] = -1e30f; l[i] = 0.f; }
    const float scale = 0.125f;   // 1/sqrt(64)

    for (int kt = 0; kt < N_ / 64; kt++) {
        __syncthreads();   // protect Ks/Vs against previous iteration's readers
#pragma unroll
        for (int i = 0; i < 4; i++) {
            int e = (t + i * 256) * 4; int r = e >> 6, c = e & 63;
            float4 kv = *reinterpret_cast<const float4*>(Kp + ((size_t)kt * 64 + r) * DK_ + c);
            Ks[r][c] = kv.x; Ks[r][c + 1] = kv.y; Ks[r][c + 2] = kv.z; Ks[r][c + 3] = kv.w;
            float4 vv = *reinterpret_cast<const float4*>(Vp + ((size_t)kt * 64 + r) * DK_ + c);
            Vs[r][c] = vv.x; Vs[r][c + 1] = vv.y; Vs[r][c + 2] = vv.z; Vs[r][c + 3] = vv.w;
        }
        __syncthreads();

        // S = Q . K^T (4x4 per thread)
        float s[4][4] = {};
#pragma unroll 8
        for (int kd = 0; kd < DK_; kd++) {
            float a[4], b[4];
#pragma unroll
            for (int i = 0; i < 4; i++) a[i] = Qs[ty * 4 + i][kd];
#pragma unroll
            for (int j = 0; j < 4; j++) b[j] = Ks[tx * 4 + j][kd];
#pragma unroll
            for (int i = 0; i < 4; i++)
#pragma unroll
                for (int j = 0; j < 4; j++) s[i][j] += a[i] * b[j];
        }

        // online softmax
#pragma unroll
        for (int i = 0; i < 4; i++) {
            float mx = -1e30f;
#pragma unroll
            for (int j = 0; j < 4; j++) { s[i][j] *= scale; mx = fmaxf(mx, s[i][j]); }
#pragma unroll
            for (int off = 8; off >= 1; off >>= 1) mx = fmaxf(mx, __shfl_xor(mx, off));
            float mnew = fmaxf(m[i], mx);
            float alpha = __expf(m[i] - mnew);
            m[i] = mnew;
            float sum = 0.f;
#pragma unroll
            for (int j = 0; j < 4; j++) { s[i][j] = __expf(s[i][j] - mnew); sum += s[i][j]; }
#pragma unroll
            for (int off = 8; off >= 1; off >>= 1) sum += __shfl_xor(sum, off);
            l[i] = l[i] * alpha + sum;
#pragma unroll
            for (int j = 0; j < 4; j++) Ps[ty * 4 + i][tx * 4 + j] = s[i][j];
#pragma unroll
            for (int j = 0; j < 4; j++) o[i][j] *= alpha;
        }
        __syncthreads();

        // O += P . V
#pragma unroll 8
        for (int kk = 0; kk < 64; kk++) {
            float p[4], v[4];
#pragma unroll
            for (int i = 0; i < 4; i++) p[i] = Ps[ty * 4 + i][kk];
#pragma unroll
            for (int j = 0; j < 4; j++) v[j] = Vs[kk][tx * 4 + j];
#pragma unroll
            for (int i = 0; i < 4; i++)
#pragma unroll
                for (int j = 0; j < 4; j++) o[i][j] += p[i] * v[j];
        }
    }

    // epilogue: normalize, write to [B,N,H*DV]
    const int b = bh >> 3, h = bh & 7;
#pragma unroll
    for (int i = 0; i < 4; i++) {
        int n = qt * 64 + ty * 4 + i;
        float inv = 1.f / l[i];
#pragma unroll
        for (int j = 0; j < 4; j++) {
            O[((size_t)(b * N_ + n)) * (H_ * DV_) + h * DV_ + tx * 4 + j] = o[i][j] * inv;
        }
    }
}

// ---------------------------------------------------------------------------
// Kernel 4: output projection  out = O[4096,512] @ Wo[512,512] + bo
// ---------------------------------------------------------------------------
__global__ __launch_bounds__(256) void proj_gemm(const float* __restrict__ Oi,
                                                 const float* __restrict__ Wo,
                                                 const float* __restrict__ bo,
                                                 float* __restrict__ out) {
    const int rt = blockIdx.x;
    const int ct = blockIdx.y;

    __shared__ float As[64][33];
    __shared__ float Bs[32][68];

    const int t  = threadIdx.x;
    const int tx = t & 15, ty = t >> 4;

    float acc[4][4] = {};

    for (int k0 = 0; k0 < DM_; k0 += 32) {
#pragma unroll
        for (int i = 0; i < 2; i++) {
            int e = (t + i * 256) * 4;
            int r = e >> 5, c = e & 31;
            float4 v = *reinterpret_cast<const float4*>(
                Oi + (size_t)(rt * 64 + r) * DM_ + k0 + c);
            As[r][c] = v.x; As[r][c + 1] = v.y; As[r][c + 2] = v.z; As[r][c + 3] = v.w;
        }
#pragma unroll
        for (int i = 0; i < 2; i++) {
            int e = (t + i * 256) * 4;
            int r = e >> 6, c = e & 63;
            float4 v = *reinterpret_cast<const float4*>(
                Wo + (size_t)(k0 + r) * DM_ + ct * 64 + c);
            Bs[r][c] = v.x; Bs[r][c + 1] = v.y; Bs[r][c + 2] = v.z; Bs[r][c + 3] = v.w;
        }
        __syncthreads();
#pragma unroll
        for (int kk = 0; kk < 32; kk++) {
            float a[4], b[4];
#pragma unroll
            for (int i = 0; i < 4; i++) a[i] = As[ty * 4 + i][kk];
#pragma unroll
            for (int j = 0; j < 4; j++) b[j] = Bs[kk][tx * 4 + j];
#pragma unroll
            for (int i = 0; i < 4; i++)
#pragma unroll
                for (int j = 0; j < 4; j++) acc[i][j] += a[i] * b[j];
        }
        __syncthreads();
    }

#pragma unroll
    for (int i = 0; i < 4; i++) {
        int row = rt * 64 + ty * 4 + i;
#pragma unroll
        for (int j = 0; j < 4; j++) {
            int col = ct * 64 + tx * 4 + j;
            out[(size_t)row * DM_ + col] = acc[i][j] + bo[col];
        }
    }
}

// ---------------------------------------------------------------------------
extern "C" void kernel_launch(void* const* d_in, const int* in_sizes, int n_in,
                              void* d_out, int out_size, void* d_ws, size_t ws_size,
                              hipStream_t stream) {
    const float* x   = (const float*)d_in[0];
    const float* Wq  = (const float*)d_in[1];
    const float* bq  = (const float*)d_in[2];
    const float* Wk  = (const float*)d_in[3];
    const float* bk  = (const float*)d_in[4];
    const float* Wv  = (const float*)d_in[5];
    const float* bv  = (const float*)d_in[6];
    const float* WqL = (const float*)d_in[7];
    const float* bqL = (const float*)d_in[8];
    const float* WkL = (const float*)d_in[9];
    const float* bkL = (const float*)d_in[10];
    const float* WvL = (const float*)d_in[11];
    const float* bvL = (const float*)d_in[12];
    const float* Wo  = (const float*)d_in[13];
    const float* bo  = (const float*)d_in[14];

    float* ws = (float*)d_ws;
    float* Wf = ws;                               // 3*512*512
    float* bf = Wf + 3 * DM_ * DM_;               // 3*512
    float* Qd = bf + 3 * DM_;                     // B*H*N*DK
    float* Kd = Qd + (size_t)B_ * H_ * N_ * DK_;
    float* Vd = Kd + (size_t)B_ * H_ * N_ * DK_;
    float* Od = Vd + (size_t)B_ * H_ * N_ * DV_;  // B*N*H*DV

    float* out = (float*)d_out;

    // 1) fuse weights
    {
        int total = 3 * DM_ * DM_;
        int blocks = (total + 255) / 256;
        fuse_wb<<<blocks, 256, 0, stream>>>(Wq, WqL, Wk, WkL, Wv, WvL,
                                            bq, bqL, bk, bkL, bv, bvL, Wf, bf);
    }
    // 2) QKV projections
    {
        dim3 grid(BN_ / 64, DM_ / 64, 3);
        qkv_gemm<<<grid, 256, 0, stream>>>(x, Wf, bf, Qd, Kd, Vd);
    }
    // 3) attention
    {
        dim3 grid(N_ / 64, B_ * H_);
        attn_fwd<<<grid, 256, 0, stream>>>(Qd, Kd, Vd, Od);
    }
    // 4) output projection
    {
        dim3 grid(BN_ / 64, DM_ / 64);
        proj_gemm<<<grid, 256, 0, stream>>>(Od, Wo, bo, out);
    }
}

// Round 2
// 233.093 us; speedup vs baseline: 2.1385x; 2.1385x over previous
//
#include <hip/hip_runtime.h>
#include <hip/hip_bf16.h>

// Problem constants
#define B_  2
#define N_  2048
#define DM_ 512
#define H_  8
#define DK_ 64
#define DV_ 64
#define BN_ (B_*N_)   // 4096 tokens

typedef __attribute__((ext_vector_type(8))) short short8;
typedef __attribute__((ext_vector_type(4))) float f32x4;
typedef unsigned short ushort;

// manual fp32 -> bf16 round-to-nearest-even
static __device__ __forceinline__ ushort f2bf(float x) {
    unsigned int u = __float_as_uint(x);
    unsigned int r = (u + 0x7FFFu + ((u >> 16) & 1u)) >> 16;
    return (ushort)r;
}

// ---------------------------------------------------------------------------
// Kernel 1: fuse base + lora weights/biases
// ---------------------------------------------------------------------------
__global__ void fuse_wb(const float* __restrict__ Wq, const float* __restrict__ WqL,
                        const float* __restrict__ Wk, const float* __restrict__ WkL,
                        const float* __restrict__ Wv, const float* __restrict__ WvL,
                        const float* __restrict__ bq, const float* __restrict__ bqL,
                        const float* __restrict__ bk, const float* __restrict__ bkL,
                        const float* __restrict__ bv, const float* __restrict__ bvL,
                        float* __restrict__ Wf, float* __restrict__ bf) {
    int idx = blockIdx.x * blockDim.x + threadIdx.x;
    const int per = DM_ * DM_;
    if (idx < 3 * per) {
        int w = idx / per, i = idx % per;
        const float* a = (w == 0) ? Wq : (w == 1) ? Wk : Wv;
        const float* b = (w == 0) ? WqL : (w == 1) ? WkL : WvL;
        Wf[idx] = a[i] + b[i];
    }
    if (idx < 3 * DM_) {
        int w = idx / DM_, i = idx % DM_;
        const float* a = (w == 0) ? bq : (w == 1) ? bk : bv;
        const float* b = (w == 0) ? bqL : (w == 1) ? bkL : bvL;
        bf[idx] = a[i] + b[i];
    }
}

// ---------------------------------------------------------------------------
// Kernel 2: QKV GEMM  [4096,512] @ [512,512] (+bias), z = {q,k,v}
// fp32 compute, writes bf16 output in [B,H,N,64] layout; Q pre-scaled by 1/8
// ---------------------------------------------------------------------------
__global__ __launch_bounds__(256) void qkv_gemm(const float* __restrict__ x,
                                                const float* __restrict__ Wf,
                                                const float* __restrict__ bf,
                                                ushort* __restrict__ Qd,
                                                ushort* __restrict__ Kd,
                                                ushort* __restrict__ Vd) {
    const int w  = blockIdx.z;
    const float* Wp = Wf + (size_t)w * DM_ * DM_;
    ushort* out = (w == 0) ? Qd : (w == 1) ? Kd : Vd;
    const int rt = blockIdx.x;
    const int ct = blockIdx.y;   // col tile (64 cols) == head index

    __shared__ float As[64][33];
    __shared__ float Bs[32][68];

    const int t  = threadIdx.x;
    const int tx = t & 15, ty = t >> 4;

    float acc[4][4] = {};

    for (int k0 = 0; k0 < DM_; k0 += 32) {
#pragma unroll
        for (int i = 0; i < 2; i++) {
            int e = (t + i * 256) * 4;
            int r = e >> 5, c = e & 31;
            float4 v = *reinterpret_cast<const float4*>(
                x + (size_t)(rt * 64 + r) * DM_ + k0 + c);
            As[r][c] = v.x; As[r][c + 1] = v.y; As[r][c + 2] = v.z; As[r][c + 3] = v.w;
        }
#pragma unroll
        for (int i = 0; i < 2; i++) {
            int e = (t + i * 256) * 4;
            int r = e >> 6, c = e & 63;
            float4 v = *reinterpret_cast<const float4*>(
                Wp + (size_t)(k0 + r) * DM_ + ct * 64 + c);
            Bs[r][c] = v.x; Bs[r][c + 1] = v.y; Bs[r][c + 2] = v.z; Bs[r][c + 3] = v.w;
        }
        __syncthreads();
#pragma unroll
        for (int kk = 0; kk < 32; kk++) {
            float a[4], b[4];
#pragma unroll
            for (int i = 0; i < 4; i++) a[i] = As[ty * 4 + i][kk];
#pragma unroll
            for (int j = 0; j < 4; j++) b[j] = Bs[kk][tx * 4 + j];
#pragma unroll
            for (int i = 0; i < 4; i++)
#pragma unroll
                for (int j = 0; j < 4; j++) acc[i][j] += a[i] * b[j];
        }
        __syncthreads();
    }

    const float qscale = (w == 0) ? 0.125f : 1.0f;
#pragma unroll
    for (int i = 0; i < 4; i++) {
        int row = rt * 64 + ty * 4 + i;
        int b = row >> 11, n = row & (N_ - 1);
#pragma unroll
        for (int j = 0; j < 4; j++) {
            int d = tx * 4 + j;
            float val = (acc[i][j] + bf[w * DM_ + ct * 64 + d]) * qscale;
            out[(((size_t)(b * H_ + ct) * N_ + n)) * DK_ + d] = f2bf(val);
        }
    }
}

// ---------------------------------------------------------------------------
// Kernel 3: flash attention with bf16 MFMA. grid = (N/64, B*H), block = 256
// Q,K,V bf16 in [B,H,N,64] (Q pre-scaled by 1/8); output fp32 in [B,N,H*DV]
//
// mfma_f32_16x16x32_bf16 layouts (verified m89/m91):
//   A[m][k]: m = lane&15, k = 8*(lane>>4)+i  (8 contiguous bf16)
//   B[k][n]: n = lane&15, k = 8*(lane>>4)+i
//   D[m][n]: m = 4*(lane>>4)+reg, n = lane&15
// LDS tiles stored row-major [row][64 bf16] with XOR swizzle:
//   byte = row*128 + ((chunk ^ (row&7))<<4) + within   (chunk = 16B unit)
// ---------------------------------------------------------------------------
__global__ __launch_bounds__(256) void attn_mfma(const ushort* __restrict__ Q,
                                                 const ushort* __restrict__ K,
                                                 const ushort* __restrict__ V,
                                                 float* __restrict__ O) {
    const int bh = blockIdx.y;
    const int qt = blockIdx.x;
    const int t  = threadIdx.x;
    const int lane = t & 63;
    const int w  = t >> 6;         // wave id, owns q rows [w*16, w*16+16)
    const int lg = lane >> 4;      // lane group 0..3
    const int lr = lane & 15;      // lane row/col 0..15

    __shared__ ushort Ks[64 * 64];       // K tile, swizzled  [key][dk]
    __shared__ ushort Vt[64 * 64];       // V^T tile, swizzled [dv][key]
    __shared__ ushort Ps[4][16 * 64];    // per-wave P tile, swizzled [q][key]

    char* KsB = (char*)Ks;
    char* VtB = (char*)Vt;
    char* PsB = (char*)(Ps[w]);

    const ushort* Kb = K + (size_t)bh * N_ * DK_;
    const ushort* Vb = V + (size_t)bh * N_ * DK_;

    // Q fragments in registers (A operand), rows w*16+lr
    short8 qf[2];
    {
        const ushort* qrow = Q + ((size_t)bh * N_ + qt * 64 + w * 16 + lr) * DK_;
        qf[0] = *reinterpret_cast<const short8*>(qrow + 8 * lg);
        qf[1] = *reinterpret_cast<const short8*>(qrow + 32 + 8 * lg);
    }

    f32x4 o_[4];                    // O accum: [dv-block], D-layout rows 4*lg+r
#pragma unroll
    for (int i = 0; i < 4; i++) o_[i] = (f32x4){0.f, 0.f, 0.f, 0.f};
    float m_[4], l_[4];
#pragma unroll
    for (int i = 0; i < 4; i++) { m_[i] = -1e30f; l_[i] = 0.f; }

    for (int kt = 0; kt < N_ / 64; ++kt) {
        __syncthreads();
        // ---- stage K (swizzled) and V^T (transposed + swizzled) ----
#pragma unroll
        for (int it = 0; it < 2; ++it) {
            int qid = t + it * 256;          // 0..511 : 64 rows x 8 chunks
            int row = qid >> 3, c = qid & 7;
            uint4 dk_ = *reinterpret_cast<const uint4*>(
                Kb + (size_t)(kt * 64 + row) * DK_ + c * 8);
            *reinterpret_cast<uint4*>(KsB + row * 128 + ((c ^ (row & 7)) << 4)) = dk_;
            uint4 dv_ = *reinterpret_cast<const uint4*>(
                Vb + (size_t)(kt * 64 + row) * DK_ + c * 8);
            const ushort* e = reinterpret_cast<const ushort*>(&dv_);
#pragma unroll
            for (int j = 0; j < 8; ++j) {
                int col = c * 8 + j;   // dv index
                // Vt[col][row]
                *reinterpret_cast<ushort*>(
                    VtB + col * 128 + (((row >> 3) ^ (col & 7)) << 4) + ((row & 7) << 1)) = e[j];
            }
        }
        __syncthreads();

        // ---- S = Q K^T : per wave [16 q][64 keys] ----
        f32x4 s[4];
#pragma unroll
        for (int kb = 0; kb < 4; ++kb) {
            int row = kb * 16 + lr;
            short8 k0 = *reinterpret_cast<const short8*>(
                KsB + row * 128 + ((lg ^ (row & 7)) << 4));
            short8 k1 = *reinterpret_cast<const short8*>(
                KsB + row * 128 + (((4 + lg) ^ (row & 7)) << 4));
            f32x4 z = (f32x4){0.f, 0.f, 0.f, 0.f};
            s[kb] = __builtin_amdgcn_mfma_f32_16x16x32_bf16(qf[0], k0, z, 0, 0, 0);
            s[kb] = __builtin_amdgcn_mfma_f32_16x16x32_bf16(qf[1], k1, s[kb], 0, 0, 0);
        }

        // ---- online softmax (per row r of this lane group) ----
#pragma unroll
        for (int r = 0; r < 4; ++r) {
            float mx = fmaxf(fmaxf(s[0][r], s[1][r]), fmaxf(s[2][r], s[3][r]));
#pragma unroll
            for (int off = 1; off < 16; off <<= 1) mx = fmaxf(mx, __shfl_xor(mx, off));
            float mnew = fmaxf(m_[r], mx);
            float alpha = __expf(m_[r] - mnew);
            m_[r] = mnew;
            float p[4];
            float sum = 0.f;
#pragma unroll
            for (int kb = 0; kb < 4; ++kb) { p[kb] = __expf(s[kb][r] - mnew); sum += p[kb]; }
#pragma unroll
            for (int off = 1; off < 16; off <<= 1) sum += __shfl_xor(sum, off);
            l_[r] = l_[r] * alpha + sum;
#pragma unroll
            for (int db = 0; db < 4; ++db) o_[db][r] *= alpha;
            // write P row (q = 4*lg + r), cols kb*16+lr, bf16, swizzled
            int prow = 4 * lg + r;
            char* pb = PsB + prow * 128;
#pragma unroll
            for (int kb = 0; kb < 4; ++kb) {
                int chunk = 2 * kb + (lr >> 3);
                *reinterpret_cast<ushort*>(
                    pb + ((chunk ^ (prow & 7)) << 4) + ((lr & 7) << 1)) = f2bf(p[kb]);
            }
        }

        // ---- O += P V : A = P fragment (rows lr), B = V^T rows ----
        short8 pf[2];
        {
            int row = lr;
            pf[0] = *reinterpret_cast<const short8*>(
                PsB + row * 128 + ((lg ^ (row & 7)) << 4));
            pf[1] = *reinterpret_cast<const short8*>(
                PsB + row * 128 + (((4 + lg) ^ (row & 7)) << 4));
        }
#pragma unroll
        for (int db = 0; db < 4; ++db) {
            int row = db * 16 + lr;
            short8 v0 = *reinterpret_cast<const short8*>(
                VtB + row * 128 + ((lg ^ (row & 7)) << 4));
            short8 v1 = *reinterpret_cast<const short8*>(
                VtB + row * 128 + (((4 + lg) ^ (row & 7)) << 4));
            o_[db] = __builtin_amdgcn_mfma_f32_16x16x32_bf16(pf[0], v0, o_[db], 0, 0, 0);
            o_[db] = __builtin_amdgcn_mfma_f32_16x16x32_bf16(pf[1], v1, o_[db], 0, 0, 0);
        }
    }

    // ---- epilogue: normalize + write [B,N,H*DV] fp32 ----
    const int b = bh >> 3, h = bh & 7;
#pragma unroll
    for (int r = 0; r < 4; ++r) {
        int n = qt * 64 + w * 16 + 4 * lg + r;
        float inv = 1.f / l_[r];
#pragma unroll
        for (int db = 0; db < 4; ++db) {
            O[((size_t)(b * N_ + n)) * (H_ * DV_) + h * DV_ + db * 16 + lr] = o_[db][r] * inv;
        }
    }
}

// ---------------------------------------------------------------------------
// Kernel 4: output projection  out = O[4096,512] @ Wo[512,512] + bo
// ---------------------------------------------------------------------------
__global__ __launch_bounds__(256) void proj_gemm(const float* __restrict__ Oi,
                                                 const float* __restrict__ Wo,
                                                 const float* __restrict__ bo,
                                                 float* __restrict__ out) {
    const int rt = blockIdx.x;
    const int ct = blockIdx.y;

    __shared__ float As[64][33];
    __shared__ float Bs[32][68];

    const int t  = threadIdx.x;
    const int tx = t & 15, ty = t >> 4;

    float acc[4][4] = {};

    for (int k0 = 0; k0 < DM_; k0 += 32) {
#pragma unroll
        for (int i = 0; i < 2; i++) {
            int e = (t + i * 256) * 4;
            int r = e >> 5, c = e & 31;
            float4 v = *reinterpret_cast<const float4*>(
                Oi + (size_t)(rt * 64 + r) * DM_ + k0 + c);
            As[r][c] = v.x; As[r][c + 1] = v.y; As[r][c + 2] = v.z; As[r][c + 3] = v.w;
        }
#pragma unroll
        for (int i = 0; i < 2; i++) {
            int e = (t + i * 256) * 4;
            int r = e >> 6, c = e & 63;
            float4 v = *reinterpret_cast<const float4*>(
                Wo + (size_t)(k0 + r) * DM_ + ct * 64 + c);
            Bs[r][c] = v.x; Bs[r][c + 1] = v.y; Bs[r][c + 2] = v.z; Bs[r][c + 3] = v.w;
        }
        __syncthreads();
#pragma unroll
        for (int kk = 0; kk < 32; kk++) {
            float a[4], b[4];
#pragma unroll
            for (int i = 0; i < 4; i++) a[i] = As[ty * 4 + i][kk];
#pragma unroll
            for (int j = 0; j < 4; j++) b[j] = Bs[kk][tx * 4 + j];
#pragma unroll
            for (int i = 0; i < 4; i++)
#pragma unroll
                for (int j = 0; j < 4; j++) acc[i][j] += a[i] * b[j];
        }
        __syncthreads();
    }

#pragma unroll
    for (int i = 0; i < 4; i++) {
        int row = rt * 64 + ty * 4 + i;
#pragma unroll
        for (int j = 0; j < 4; j++) {
            int col = ct * 64 + tx * 4 + j;
            out[(size_t)row * DM_ + col] = acc[i][j] + bo[col];
        }
    }
}

// ---------------------------------------------------------------------------
extern "C" void kernel_launch(void* const* d_in, const int* in_sizes, int n_in,
                              void* d_out, int out_size, void* d_ws, size_t ws_size,
                              hipStream_t stream) {
    const float* x   = (const float*)d_in[0];
    const float* Wq  = (const float*)d_in[1];
    const float* bq  = (const float*)d_in[2];
    const float* Wk  = (const float*)d_in[3];
    const float* bk  = (const float*)d_in[4];
    const float* Wv  = (const float*)d_in[5];
    const float* bv  = (const float*)d_in[6];
    const float* WqL = (const float*)d_in[7];
    const float* bqL = (const float*)d_in[8];
    const float* WkL = (const float*)d_in[9];
    const float* bkL = (const float*)d_in[10];
    const float* WvL = (const float*)d_in[11];
    const float* bvL = (const float*)d_in[12];
    const float* Wo  = (const float*)d_in[13];
    const float* bo  = (const float*)d_in[14];

    float* Wf = (float*)d_ws;                        // 3*512*512 f32
    float* bfv = Wf + 3 * DM_ * DM_;                 // 3*512 f32
    ushort* Qd = (ushort*)(bfv + 3 * DM_);           // B*H*N*DK bf16
    ushort* Kd = Qd + (size_t)B_ * H_ * N_ * DK_;
    ushort* Vd = Kd + (size_t)B_ * H_ * N_ * DK_;
    float* Od  = (float*)(Vd + (size_t)B_ * H_ * N_ * DV_);  // B*N*H*DV f32

    float* out = (float*)d_out;

    {
        int total = 3 * DM_ * DM_;
        int blocks = (total + 255) / 256;
        fuse_wb<<<blocks, 256, 0, stream>>>(Wq, WqL, Wk, WkL, Wv, WvL,
                                            bq, bqL, bk, bkL, bv, bvL, Wf, bfv);
    }
    {
        dim3 grid(BN_ / 64, DM_ / 64, 3);
        qkv_gemm<<<grid, 256, 0, stream>>>(x, Wf, bfv, Qd, Kd, Vd);
    }
    {
        dim3 grid(N_ / 64, B_ * H_);
        attn_mfma<<<grid, 256, 0, stream>>>(Qd, Kd, Vd, Od);
    }
    {
        dim3 grid(BN_ / 64, DM_ / 64);
        proj_gemm<<<grid, 256, 0, stream>>>(Od, Wo, bo, out);
    }
}

// Round 3
// 110.975 us; speedup vs baseline: 4.4918x; 2.1004x over previous
//
#include <hip/hip_runtime.h>
#include <hip/hip_bf16.h>

// Problem constants
#define B_  2
#define N_  2048
#define DM_ 512
#define H_  8
#define DK_ 64
#define DV_ 64
#define BN_ (B_*N_)   // 4096 tokens

typedef __attribute__((ext_vector_type(8))) short short8;
typedef __attribute__((ext_vector_type(4))) float f32x4;
typedef unsigned short ushort;

// fp32 -> bf16 round-to-nearest-even
static __device__ __forceinline__ ushort f2bf(float x) {
    unsigned int u = __float_as_uint(x);
    unsigned int r = (u + 0x7FFFu + ((u >> 16) & 1u)) >> 16;
    return (ushort)r;
}

// ---------------------------------------------------------------------------
// fuse_transpose: Wt[n][k] = bf16(W[k][n] + WL[k][n]).  W is [512][512] f32.
// grid (8,16) = (n/64, k/32), 256 threads.
// ---------------------------------------------------------------------------
__global__ __launch_bounds__(256) void fuse_transpose(const float* __restrict__ W,
                                                      const float* __restrict__ WL,
                                                      ushort* __restrict__ Wt) {
    __shared__ float Ws[32][65];
    const int t  = threadIdx.x;
    const int c0 = blockIdx.x * 64;
    const int k0 = blockIdx.y * 32;
    {
        int r = t >> 4, cq = t & 15;
#pragma unroll
        for (int it = 0; it < 2; ++it) {
            int rr = r + it * 16;
            float4 v = *reinterpret_cast<const float4*>(W + (size_t)(k0 + rr) * DM_ + c0 + cq * 4);
            if (WL) {
                float4 u = *reinterpret_cast<const float4*>(WL + (size_t)(k0 + rr) * DM_ + c0 + cq * 4);
                v.x += u.x; v.y += u.y; v.z += u.z; v.w += u.w;
            }
            Ws[rr][cq * 4 + 0] = v.x; Ws[rr][cq * 4 + 1] = v.y;
            Ws[rr][cq * 4 + 2] = v.z; Ws[rr][cq * 4 + 3] = v.w;
        }
    }
    __syncthreads();
    {
        int cr = t >> 2, kq = t & 3;
        short8 o;
#pragma unroll
        for (int j = 0; j < 8; ++j) o[j] = (short)f2bf(Ws[kq * 8 + j][cr]);
        *reinterpret_cast<short8*>(Wt + (size_t)(c0 + cr) * DM_ + k0 + kq * 8) = o;
    }
}

// ---------------------------------------------------------------------------
// fuse_bias: fb[1536] = b + bL  (q,k,v sections)
// ---------------------------------------------------------------------------
__global__ void fuse_bias(const float* __restrict__ bq, const float* __restrict__ bqL,
                          const float* __restrict__ bk, const float* __restrict__ bkL,
                          const float* __restrict__ bv, const float* __restrict__ bvL,
                          float* __restrict__ fb) {
    int idx = blockIdx.x * blockDim.x + threadIdx.x;
    if (idx >= 3 * DM_) return;
    int w = idx >> 9, i = idx & 511;
    const float* a = (w == 0) ? bq : (w == 1) ? bk : bv;
    const float* b = (w == 0) ? bqL : (w == 1) ? bkL : bvL;
    fb[idx] = a[i] + b[i];
}

// ---------------------------------------------------------------------------
// xcast: x f32 [4096*512] -> bf16
// ---------------------------------------------------------------------------
__global__ void xcast(const float* __restrict__ x, ushort* __restrict__ xb) {
    size_t idx = (size_t)blockIdx.x * blockDim.x + threadIdx.x;   // 0..262143
    float4 v0 = *reinterpret_cast<const float4*>(x + idx * 8);
    float4 v1 = *reinterpret_cast<const float4*>(x + idx * 8 + 4);
    short8 o;
    o[0] = (short)f2bf(v0.x); o[1] = (short)f2bf(v0.y);
    o[2] = (short)f2bf(v0.z); o[3] = (short)f2bf(v0.w);
    o[4] = (short)f2bf(v1.x); o[5] = (short)f2bf(v1.y);
    o[6] = (short)f2bf(v1.z); o[7] = (short)f2bf(v1.w);
    *reinterpret_cast<short8*>(xb + idx * 8) = o;
}

// ---------------------------------------------------------------------------
// gemm_bf16: C[M][Ncols] = A[M][512] @ Bt[Ncols][512]^T + bias
// BM=128, BK=64, 256 threads (4 waves). LDS XOR-swizzled (T2, both sides).
// MODE 0: qkv epilogue (bf16 [B,H,N,64], Q scaled 1/8). MODE 1: fp32 out.
// ---------------------------------------------------------------------------
template<int BN, int MODE>
__global__ __launch_bounds__(256) void gemm_bf16(const ushort* __restrict__ A,
                                                 const ushort* __restrict__ Bt,
                                                 const float* __restrict__ bias,
                                                 ushort* __restrict__ Qd,
                                                 ushort* __restrict__ Kd,
                                                 ushort* __restrict__ Vd,
                                                 float* __restrict__ outF) {
    constexpr int NWC = BN / 64;          // waves along N
    constexpr int NWR = 4 / NWC;          // waves along M
    constexpr int MI  = (128 / NWR) / 16; // m-frags per wave
    constexpr int NJ  = 4;                // n-frags per wave
    const int rt = blockIdx.x, ct = blockIdx.y;
    __shared__ ushort As[128 * 64];
    __shared__ ushort Bs[BN * 64];
    const int t = threadIdx.x, lane = t & 63, w = t >> 6;
    const int wr = w / NWC, wc = w % NWC;
    const int lg = lane >> 4, lr = lane & 15;
    const int rowbase = wr * (128 / NWR);
    const int colbase = wc * 64;

    f32x4 acc[MI][NJ];
#pragma unroll
    for (int mi = 0; mi < MI; ++mi)
#pragma unroll
        for (int nj = 0; nj < NJ; ++nj) acc[mi][nj] = (f32x4){0.f, 0.f, 0.f, 0.f};

    for (int k0 = 0; k0 < DM_; k0 += 64) {
        __syncthreads();
#pragma unroll
        for (int it = 0; it < 4; ++it) {           // A: 128x64 bf16 = 1024 chunks
            int cid = t + it * 256;
            int r = cid >> 3, cq = cid & 7;
            uint4 vld = *reinterpret_cast<const uint4*>(
                A + ((size_t)(rt * 128 + r)) * DM_ + k0 + cq * 8);
            *reinterpret_cast<uint4*>((char*)As + r * 128 + ((cq ^ (r & 7)) << 4)) = vld;
        }
#pragma unroll
        for (int it = 0; it < BN * 8 / 256; ++it) { // B: BNx64 bf16
            int cid = t + it * 256;
            int r = cid >> 3, cq = cid & 7;
            uint4 vld = *reinterpret_cast<const uint4*>(
                Bt + ((size_t)(ct * BN + r)) * DM_ + k0 + cq * 8);
            *reinterpret_cast<uint4*>((char*)Bs + r * 128 + ((cq ^ (r & 7)) << 4)) = vld;
        }
        __syncthreads();
#pragma unroll
        for (int kh = 0; kh < 2; ++kh) {
            short8 a[MI], b[NJ];
#pragma unroll
            for (int mi = 0; mi < MI; ++mi) {
                int row = rowbase + mi * 16 + lr;
                a[mi] = *reinterpret_cast<const short8*>(
                    (char*)As + row * 128 + (((kh * 4 + lg) ^ (row & 7)) << 4));
            }
#pragma unroll
            for (int nj = 0; nj < NJ; ++nj) {
                int row = colbase + nj * 16 + lr;
                b[nj] = *reinterpret_cast<const short8*>(
                    (char*)Bs + row * 128 + (((kh * 4 + lg) ^ (row & 7)) << 4));
            }
#pragma unroll
            for (int mi = 0; mi < MI; ++mi)
#pragma unroll
                for (int nj = 0; nj < NJ; ++nj)
                    acc[mi][nj] = __builtin_amdgcn_mfma_f32_16x16x32_bf16(
                        a[mi], b[nj], acc[mi][nj], 0, 0, 0);
        }
    }

#pragma unroll
    for (int mi = 0; mi < MI; ++mi) {
#pragma unroll
        for (int nj = 0; nj < NJ; ++nj) {
#pragma unroll
            for (int r = 0; r < 4; ++r) {
                int m = rt * 128 + rowbase + mi * 16 + 4 * lg + r;
                int n = ct * BN + colbase + nj * 16 + lr;
                float v = acc[mi][nj][r] + bias[n];
                if (MODE == 0) {
                    int ws_ = n >> 9;
                    if (ws_ == 0) v *= 0.125f;
                    ushort* op = (ws_ == 0) ? Qd : (ws_ == 1) ? Kd : Vd;
                    int hd = (n >> 6) & 7, d = n & 63;
                    int bb = m >> 11, nn = m & (N_ - 1);
                    op[(((size_t)(bb * H_ + hd)) * N_ + nn) * DK_ + d] = f2bf(v);
                } else {
                    outF[(size_t)m * DM_ + n] = v;
                }
            }
        }
    }
}

// ---------------------------------------------------------------------------
// attn: flash attention, bf16 MFMA, double-buffered K/V^T, ONE barrier/tile.
// grid (N/64, B*H), 256 threads (4 waves, 16 q-rows each).
// Q pre-scaled 1/8. Output bf16 [B,N,H*DV].
// ---------------------------------------------------------------------------
__global__ __launch_bounds__(256) void attn_mfma(const ushort* __restrict__ Q,
                                                 const ushort* __restrict__ K,
                                                 const ushort* __restrict__ V,
                                                 ushort* __restrict__ O) {
    const int bh = blockIdx.y;
    const int qt = blockIdx.x;
    const int t  = threadIdx.x;
    const int lane = t & 63;
    const int w  = t >> 6;
    const int lg = lane >> 4;
    const int lr = lane & 15;

    __shared__ ushort KsBuf[2][64 * 64];
    __shared__ ushort VtBuf[2][64 * 64];
    __shared__ ushort Ps[4][16 * 64];

    char* PsB = (char*)(Ps[w]);

    const ushort* Kb = K + (size_t)bh * N_ * DK_;
    const ushort* Vb = V + (size_t)bh * N_ * DK_;

    // staging maps
    const int krow0 = t >> 3, kc = t & 7;   // K rows 0..31 / 32..63
    const int krow1 = krow0 + 32;
    const int kp = t & 31, vc = t >> 5;     // V: key pair kp, dv-chunk vc

    short8 qf[2];
    {
        const ushort* qrow = Q + ((size_t)bh * N_ + qt * 64 + w * 16 + lr) * DK_;
        qf[0] = *reinterpret_cast<const short8*>(qrow + 8 * lg);
        qf[1] = *reinterpret_cast<const short8*>(qrow + 32 + 8 * lg);
    }

    f32x4 o_[4];
#pragma unroll
    for (int i = 0; i < 4; i++) o_[i] = (f32x4){0.f, 0.f, 0.f, 0.f};
    float m_[4], l_[4];
#pragma unroll
    for (int i = 0; i < 4; i++) { m_[i] = -1e30f; l_[i] = 0.f; }

    uint4 kreg0, kreg1, vreg0, vreg1;

    auto issue = [&](int kt_) {
        kreg0 = *reinterpret_cast<const uint4*>(Kb + ((size_t)(kt_ * 64 + krow0)) * DK_ + kc * 8);
        kreg1 = *reinterpret_cast<const uint4*>(Kb + ((size_t)(kt_ * 64 + krow1)) * DK_ + kc * 8);
        vreg0 = *reinterpret_cast<const uint4*>(Vb + ((size_t)(kt_ * 64 + 2 * kp)) * DK_ + vc * 8);
        vreg1 = *reinterpret_cast<const uint4*>(Vb + ((size_t)(kt_ * 64 + 2 * kp + 1)) * DK_ + vc * 8);
    };
    auto wstage = [&](int buf_) {
        char* KsB = (char*)(KsBuf[buf_]);
        *reinterpret_cast<uint4*>(KsB + krow0 * 128 + ((kc ^ (krow0 & 7)) << 4)) = kreg0;
        *reinterpret_cast<uint4*>(KsB + krow1 * 128 + ((kc ^ (krow1 & 7)) << 4)) = kreg1;
        char* VtB = (char*)(VtBuf[buf_]);
        const ushort* e0 = reinterpret_cast<const ushort*>(&vreg0);
        const ushort* e1 = reinterpret_cast<const ushort*>(&vreg1);
#pragma unroll
        for (int j = 0; j < 8; ++j) {
            int col = vc * 8 + j;     // dv index
            unsigned pack = (unsigned)e0[j] | ((unsigned)e1[j] << 16);
            *reinterpret_cast<unsigned*>(
                VtB + col * 128 + (((kp >> 2) ^ (col & 7)) << 4) + (kp & 3) * 4) = pack;
        }
    };

    issue(0);
    wstage(0);
    __syncthreads();

    for (int kt = 0; kt < N_ / 64; ++kt) {
        const int cur = kt & 1;
        if (kt + 1 < N_ / 64) issue(kt + 1);

        char* KsB = (char*)(KsBuf[cur]);
        char* VtB = (char*)(VtBuf[cur]);

        // ---- S = Q K^T ----
        f32x4 s[4];
#pragma unroll
        for (int kb = 0; kb < 4; ++kb) {
            int row = kb * 16 + lr;
            short8 k0 = *reinterpret_cast<const short8*>(
                KsB + row * 128 + ((lg ^ (row & 7)) << 4));
            short8 k1 = *reinterpret_cast<const short8*>(
                KsB + row * 128 + (((4 + lg) ^ (row & 7)) << 4));
            f32x4 z = (f32x4){0.f, 0.f, 0.f, 0.f};
            s[kb] = __builtin_amdgcn_mfma_f32_16x16x32_bf16(qf[0], k0, z, 0, 0, 0);
            s[kb] = __builtin_amdgcn_mfma_f32_16x16x32_bf16(qf[1], k1, s[kb], 0, 0, 0);
        }

        // ---- online softmax ----
#pragma unroll
        for (int r = 0; r < 4; ++r) {
            float mx = fmaxf(fmaxf(s[0][r], s[1][r]), fmaxf(s[2][r], s[3][r]));
#pragma unroll
            for (int off = 1; off < 16; off <<= 1) mx = fmaxf(mx, __shfl_xor(mx, off));
            float mnew = fmaxf(m_[r], mx);
            float alpha = __expf(m_[r] - mnew);
            m_[r] = mnew;
            float p[4];
            float sum = 0.f;
#pragma unroll
            for (int kb = 0; kb < 4; ++kb) { p[kb] = __expf(s[kb][r] - mnew); sum += p[kb]; }
#pragma unroll
            for (int off = 1; off < 16; off <<= 1) sum += __shfl_xor(sum, off);
            l_[r] = l_[r] * alpha + sum;
#pragma unroll
            for (int db = 0; db < 4; ++db) o_[db][r] *= alpha;
            int prow = 4 * lg + r;
            char* pb = PsB + prow * 128;
#pragma unroll
            for (int kb = 0; kb < 4; ++kb) {
                int chunk = 2 * kb + (lr >> 3);
                *reinterpret_cast<ushort*>(
                    pb + ((chunk ^ (prow & 7)) << 4) + ((lr & 7) << 1)) = f2bf(p[kb]);
            }
        }

        // ---- O += P V ----
        short8 pf[2];
        {
            int row = lr;
            pf[0] = *reinterpret_cast<const short8*>(
                PsB + row * 128 + ((lg ^ (row & 7)) << 4));
            pf[1] = *reinterpret_cast<const short8*>(
                PsB + row * 128 + (((4 + lg) ^ (row & 7)) << 4));
        }
#pragma unroll
        for (int db = 0; db < 4; ++db) {
            int row = db * 16 + lr;
            short8 v0 = *reinterpret_cast<const short8*>(
                VtB + row * 128 + ((lg ^ (row & 7)) << 4));
            short8 v1 = *reinterpret_cast<const short8*>(
                VtB + row * 128 + (((4 + lg) ^ (row & 7)) << 4));
            o_[db] = __builtin_amdgcn_mfma_f32_16x16x32_bf16(pf[0], v0, o_[db], 0, 0, 0);
            o_[db] = __builtin_amdgcn_mfma_f32_16x16x32_bf16(pf[1], v1, o_[db], 0, 0, 0);
        }

        if (kt + 1 < N_ / 64) wstage(cur ^ 1);
        __syncthreads();
    }

    // ---- epilogue: normalize + write bf16 [B,N,H*DV] ----
    const int b = bh >> 3, h = bh & 7;
#pragma unroll
    for (int r = 0; r < 4; ++r) {
        int n = qt * 64 + w * 16 + 4 * lg + r;
        float inv = 1.f / l_[r];
#pragma unroll
        for (int db = 0; db < 4; ++db) {
            O[((size_t)(b * N_ + n)) * (H_ * DV_) + h * DV_ + db * 16 + lr] =
                f2bf(o_[db][r] * inv);
        }
    }
}

// ---------------------------------------------------------------------------
extern "C" void kernel_launch(void* const* d_in, const int* in_sizes, int n_in,
                              void* d_out, int out_size, void* d_ws, size_t ws_size,
                              hipStream_t stream) {
    const float* x   = (const float*)d_in[0];
    const float* Wq  = (const float*)d_in[1];
    const float* bq  = (const float*)d_in[2];
    const float* Wk  = (const float*)d_in[3];
    const float* bk  = (const float*)d_in[4];
    const float* Wv  = (const float*)d_in[5];
    const float* bv  = (const float*)d_in[6];
    const float* WqL = (const float*)d_in[7];
    const float* bqL = (const float*)d_in[8];
    const float* WkL = (const float*)d_in[9];
    const float* bkL = (const float*)d_in[10];
    const float* WvL = (const float*)d_in[11];
    const float* bvL = (const float*)d_in[12];
    const float* Wo  = (const float*)d_in[13];
    const float* bo  = (const float*)d_in[14];

    ushort* Wt_qkv = (ushort*)d_ws;                    // [1536][512] bf16
    ushort* Wot    = Wt_qkv + (size_t)3 * DM_ * DM_;   // [512][512] bf16
    float*  fb     = (float*)(Wot + (size_t)DM_ * DM_);// [1536] f32
    ushort* xbf    = (ushort*)(fb + 3 * DM_);          // [4096][512] bf16
    ushort* Qd     = xbf + (size_t)BN_ * DM_;
    ushort* Kd     = Qd + (size_t)B_ * H_ * N_ * DK_;
    ushort* Vd     = Kd + (size_t)B_ * H_ * N_ * DK_;
    ushort* Od     = Vd + (size_t)B_ * H_ * N_ * DV_;  // [B,N,H*DV] bf16

    float* out = (float*)d_out;

    fuse_transpose<<<dim3(8, 16), 256, 0, stream>>>(Wq, WqL, Wt_qkv);
    fuse_transpose<<<dim3(8, 16), 256, 0, stream>>>(Wk, WkL, Wt_qkv + (size_t)DM_ * DM_);
    fuse_transpose<<<dim3(8, 16), 256, 0, stream>>>(Wv, WvL, Wt_qkv + (size_t)2 * DM_ * DM_);
    fuse_transpose<<<dim3(8, 16), 256, 0, stream>>>(Wo, nullptr, Wot);
    fuse_bias<<<6, 256, 0, stream>>>(bq, bqL, bk, bkL, bv, bvL, fb);
    xcast<<<1024, 256, 0, stream>>>(x, xbf);

    gemm_bf16<128, 0><<<dim3(32, 12), 256, 0, stream>>>(xbf, Wt_qkv, fb, Qd, Kd, Vd, nullptr);
    attn_mfma<<<dim3(32, 16), 256, 0, stream>>>(Qd, Kd, Vd, Od);
    gemm_bf16<64, 1><<<dim3(32, 8), 256, 0, stream>>>(Od, Wot, bo, nullptr, nullptr, nullptr, out);
}

// Round 4
// 80.984 us; speedup vs baseline: 6.1553x; 1.3703x over previous
//
#include <hip/hip_runtime.h>
#include <hip/hip_bf16.h>

// Problem constants
#define B_  2
#define N_  2048
#define DM_ 512
#define H_  8
#define DK_ 64
#define DV_ 64
#define BN_ (B_*N_)   // 4096 tokens

typedef __attribute__((ext_vector_type(8))) short short8;
typedef __attribute__((ext_vector_type(4))) float f32x4;
typedef unsigned short ushort;

// fp32 -> bf16 round-to-nearest-even
static __device__ __forceinline__ ushort f2bf(float x) {
    unsigned int u = __float_as_uint(x);
    unsigned int r = (u + 0x7FFFu + ((u >> 16) & 1u)) >> 16;
    return (ushort)r;
}

// ---------------------------------------------------------------------------
// fuse_transpose4: Wt[z][n][k] = bf16(W_z[k][n] + WL_z[k][n]); z=3 has no lora.
// grid (8,16,4), 256 threads.
// ---------------------------------------------------------------------------
__global__ __launch_bounds__(256) void fuse_transpose4(
        const float* __restrict__ W0, const float* __restrict__ L0,
        const float* __restrict__ W1, const float* __restrict__ L1,
        const float* __restrict__ W2, const float* __restrict__ L2,
        const float* __restrict__ W3, ushort* __restrict__ WtBase) {
    const int z = blockIdx.z;
    const float* W  = (z == 0) ? W0 : (z == 1) ? W1 : (z == 2) ? W2 : W3;
    const float* WL = (z == 0) ? L0 : (z == 1) ? L1 : (z == 2) ? L2 : nullptr;
    ushort* Wt = WtBase + (size_t)z * DM_ * DM_;

    __shared__ float Ws[32][65];
    const int t  = threadIdx.x;
    const int c0 = blockIdx.x * 64;
    const int k0 = blockIdx.y * 32;
    {
        int r = t >> 4, cq = t & 15;
#pragma unroll
        for (int it = 0; it < 2; ++it) {
            int rr = r + it * 16;
            float4 v = *reinterpret_cast<const float4*>(W + (size_t)(k0 + rr) * DM_ + c0 + cq * 4);
            if (WL) {
                float4 u = *reinterpret_cast<const float4*>(WL + (size_t)(k0 + rr) * DM_ + c0 + cq * 4);
                v.x += u.x; v.y += u.y; v.z += u.z; v.w += u.w;
            }
            Ws[rr][cq * 4 + 0] = v.x; Ws[rr][cq * 4 + 1] = v.y;
            Ws[rr][cq * 4 + 2] = v.z; Ws[rr][cq * 4 + 3] = v.w;
        }
    }
    __syncthreads();
    {
        int cr = t >> 2, kq = t & 3;
        short8 o;
#pragma unroll
        for (int j = 0; j < 8; ++j) o[j] = (short)f2bf(Ws[kq * 8 + j][cr]);
        *reinterpret_cast<short8*>(Wt + (size_t)(c0 + cr) * DM_ + k0 + kq * 8) = o;
    }
}

// ---------------------------------------------------------------------------
// fuse_bias: fb[1536] = b + bL  (q,k,v sections)
// ---------------------------------------------------------------------------
__global__ void fuse_bias(const float* __restrict__ bq, const float* __restrict__ bqL,
                          const float* __restrict__ bk, const float* __restrict__ bkL,
                          const float* __restrict__ bv, const float* __restrict__ bvL,
                          float* __restrict__ fb) {
    int idx = blockIdx.x * blockDim.x + threadIdx.x;
    if (idx >= 3 * DM_) return;
    int w = idx >> 9, i = idx & 511;
    const float* a = (w == 0) ? bq : (w == 1) ? bk : bv;
    const float* b = (w == 0) ? bqL : (w == 1) ? bkL : bvL;
    fb[idx] = a[i] + b[i];
}

// ---------------------------------------------------------------------------
// xcast: x f32 [4096*512] -> bf16
// ---------------------------------------------------------------------------
__global__ void xcast(const float* __restrict__ x, ushort* __restrict__ xb) {
    size_t idx = (size_t)blockIdx.x * blockDim.x + threadIdx.x;
    float4 v0 = *reinterpret_cast<const float4*>(x + idx * 8);
    float4 v1 = *reinterpret_cast<const float4*>(x + idx * 8 + 4);
    short8 o;
    o[0] = (short)f2bf(v0.x); o[1] = (short)f2bf(v0.y);
    o[2] = (short)f2bf(v0.z); o[3] = (short)f2bf(v0.w);
    o[4] = (short)f2bf(v1.x); o[5] = (short)f2bf(v1.y);
    o[6] = (short)f2bf(v1.z); o[7] = (short)f2bf(v1.w);
    *reinterpret_cast<short8*>(xb + idx * 8) = o;
}

// ---------------------------------------------------------------------------
// gemm_bf16: C[M][Ncols] = A[M][512] @ Bt[Ncols][512]^T + bias
// BM=128, BK=64, 256 threads (4 waves). LDS XOR-swizzled (T2, both sides).
// MODE 0: qkv epilogue (bf16 [B,H,N,64], Q scaled 1/8). MODE 1: fp32 out.
// ---------------------------------------------------------------------------
template<int BN, int MODE>
__global__ __launch_bounds__(256) void gemm_bf16(const ushort* __restrict__ A,
                                                 const ushort* __restrict__ Bt,
                                                 const float* __restrict__ bias,
                                                 ushort* __restrict__ Qd,
                                                 ushort* __restrict__ Kd,
                                                 ushort* __restrict__ Vd,
                                                 float* __restrict__ outF) {
    constexpr int NWC = BN / 64;
    constexpr int NWR = 4 / NWC;
    constexpr int MI  = (128 / NWR) / 16;
    constexpr int NJ  = 4;
    const int rt = blockIdx.x, ct = blockIdx.y;
    __shared__ ushort As[128 * 64];
    __shared__ ushort Bs[BN * 64];
    const int t = threadIdx.x, lane = t & 63, w = t >> 6;
    const int wr = w / NWC, wc = w % NWC;
    const int lg = lane >> 4, lr = lane & 15;
    const int rowbase = wr * (128 / NWR);
    const int colbase = wc * 64;

    f32x4 acc[MI][NJ];
#pragma unroll
    for (int mi = 0; mi < MI; ++mi)
#pragma unroll
        for (int nj = 0; nj < NJ; ++nj) acc[mi][nj] = (f32x4){0.f, 0.f, 0.f, 0.f};

    for (int k0 = 0; k0 < DM_; k0 += 64) {
        __syncthreads();
#pragma unroll
        for (int it = 0; it < 4; ++it) {
            int cid = t + it * 256;
            int r = cid >> 3, cq = cid & 7;
            uint4 vld = *reinterpret_cast<const uint4*>(
                A + ((size_t)(rt * 128 + r)) * DM_ + k0 + cq * 8);
            *reinterpret_cast<uint4*>((char*)As + r * 128 + ((cq ^ (r & 7)) << 4)) = vld;
        }
#pragma unroll
        for (int it = 0; it < BN * 8 / 256; ++it) {
            int cid = t + it * 256;
            int r = cid >> 3, cq = cid & 7;
            uint4 vld = *reinterpret_cast<const uint4*>(
                Bt + ((size_t)(ct * BN + r)) * DM_ + k0 + cq * 8);
            *reinterpret_cast<uint4*>((char*)Bs + r * 128 + ((cq ^ (r & 7)) << 4)) = vld;
        }
        __syncthreads();
#pragma unroll
        for (int kh = 0; kh < 2; ++kh) {
            short8 a[MI], b[NJ];
#pragma unroll
            for (int mi = 0; mi < MI; ++mi) {
                int row = rowbase + mi * 16 + lr;
                a[mi] = *reinterpret_cast<const short8*>(
                    (char*)As + row * 128 + (((kh * 4 + lg) ^ (row & 7)) << 4));
            }
#pragma unroll
            for (int nj = 0; nj < NJ; ++nj) {
                int row = colbase + nj * 16 + lr;
                b[nj] = *reinterpret_cast<const short8*>(
                    (char*)Bs + row * 128 + (((kh * 4 + lg) ^ (row & 7)) << 4));
            }
#pragma unroll
            for (int mi = 0; mi < MI; ++mi)
#pragma unroll
                for (int nj = 0; nj < NJ; ++nj)
                    acc[mi][nj] = __builtin_amdgcn_mfma_f32_16x16x32_bf16(
                        a[mi], b[nj], acc[mi][nj], 0, 0, 0);
        }
    }

#pragma unroll
    for (int mi = 0; mi < MI; ++mi) {
#pragma unroll
        for (int nj = 0; nj < NJ; ++nj) {
#pragma unroll
            for (int r = 0; r < 4; ++r) {
                int m = rt * 128 + rowbase + mi * 16 + 4 * lg + r;
                int n = ct * BN + colbase + nj * 16 + lr;
                float v = acc[mi][nj][r] + bias[n];
                if (MODE == 0) {
                    int ws_ = n >> 9;
                    if (ws_ == 0) v *= 0.125f;
                    ushort* op = (ws_ == 0) ? Qd : (ws_ == 1) ? Kd : Vd;
                    int hd = (n >> 6) & 7, d = n & 63;
                    int bb = m >> 11, nn = m & (N_ - 1);
                    op[(((size_t)(bb * H_ + hd)) * N_ + nn) * DK_ + d] = f2bf(v);
                } else {
                    outF[(size_t)m * DM_ + n] = v;
                }
            }
        }
    }
}

// ---------------------------------------------------------------------------
// attn: flash attention, bf16 MFMA, SWAPPED QK^T (S^T = K@Q^T) so softmax
// rows are lane-local. Double-buffered K/V^T, one barrier/tile.
// grid (N/64, B*H), 256 threads (4 waves, 16 q-rows each).
// Q pre-scaled 1/8. Output bf16 [B,N,H*DV].
// ---------------------------------------------------------------------------
__global__ __launch_bounds__(256) void attn_mfma(const ushort* __restrict__ Q,
                                                 const ushort* __restrict__ K,
                                                 const ushort* __restrict__ V,
                                                 ushort* __restrict__ O) {
    const int bh = blockIdx.y;
    const int qt = blockIdx.x;
    const int t  = threadIdx.x;
    const int lane = t & 63;
    const int w  = t >> 6;
    const int lg = lane >> 4;
    const int lr = lane & 15;

    __shared__ ushort KsBuf[2][64 * 64];
    __shared__ ushort VtBuf[2][64 * 64];
    __shared__ ushort Ps[4][16 * 64];

    char* PsB = (char*)(Ps[w]);

    const ushort* Kb = K + (size_t)bh * N_ * DK_;
    const ushort* Vb = V + (size_t)bh * N_ * DK_;

    const int krow0 = t >> 3, kc = t & 7;
    const int krow1 = krow0 + 32;
    const int kp = t & 31, vc = t >> 5;

    short8 qf[2];
    {
        const ushort* qrow = Q + ((size_t)bh * N_ + qt * 64 + w * 16 + lr) * DK_;
        qf[0] = *reinterpret_cast<const short8*>(qrow + 8 * lg);
        qf[1] = *reinterpret_cast<const short8*>(qrow + 32 + 8 * lg);
    }

    f32x4 o_[4];
#pragma unroll
    for (int i = 0; i < 4; i++) o_[i] = (f32x4){0.f, 0.f, 0.f, 0.f};
    float m1 = -1e30f, l1 = 0.f;   // per-lane softmax state for q = lr

    uint4 kreg0, kreg1, vreg0, vreg1;

    auto issue = [&](int kt_) {
        kreg0 = *reinterpret_cast<const uint4*>(Kb + ((size_t)(kt_ * 64 + krow0)) * DK_ + kc * 8);
        kreg1 = *reinterpret_cast<const uint4*>(Kb + ((size_t)(kt_ * 64 + krow1)) * DK_ + kc * 8);
        vreg0 = *reinterpret_cast<const uint4*>(Vb + ((size_t)(kt_ * 64 + 2 * kp)) * DK_ + vc * 8);
        vreg1 = *reinterpret_cast<const uint4*>(Vb + ((size_t)(kt_ * 64 + 2 * kp + 1)) * DK_ + vc * 8);
    };
    auto wstage = [&](int buf_) {
        char* KsB = (char*)(KsBuf[buf_]);
        *reinterpret_cast<uint4*>(KsB + krow0 * 128 + ((kc ^ (krow0 & 7)) << 4)) = kreg0;
        *reinterpret_cast<uint4*>(KsB + krow1 * 128 + ((kc ^ (krow1 & 7)) << 4)) = kreg1;
        char* VtB = (char*)(VtBuf[buf_]);
        const ushort* e0 = reinterpret_cast<const ushort*>(&vreg0);
        const ushort* e1 = reinterpret_cast<const ushort*>(&vreg1);
#pragma unroll
        for (int j = 0; j < 8; ++j) {
            int col = vc * 8 + j;
            unsigned pack = (unsigned)e0[j] | ((unsigned)e1[j] << 16);
            *reinterpret_cast<unsigned*>(
                VtB + col * 128 + (((kp >> 2) ^ (col & 7)) << 4) + (kp & 3) * 4) = pack;
        }
    };

    issue(0);
    wstage(0);
    __syncthreads();

    for (int kt = 0; kt < N_ / 64; ++kt) {
        const int cur = kt & 1;
        if (kt + 1 < N_ / 64) issue(kt + 1);

        char* KsB = (char*)(KsBuf[cur]);
        char* VtB = (char*)(VtBuf[cur]);

        // ---- S^T = K Q^T : lane holds S[key=kb*16+4lg+r][q=lr] ----
        f32x4 s[4];
#pragma unroll
        for (int kb = 0; kb < 4; ++kb) {
            int row = kb * 16 + lr;
            short8 k0 = *reinterpret_cast<const short8*>(
                KsB + row * 128 + ((lg ^ (row & 7)) << 4));
            short8 k1 = *reinterpret_cast<const short8*>(
                KsB + row * 128 + (((4 + lg) ^ (row & 7)) << 4));
            f32x4 z = (f32x4){0.f, 0.f, 0.f, 0.f};
            s[kb] = __builtin_amdgcn_mfma_f32_16x16x32_bf16(k0, qf[0], z, 0, 0, 0);
            s[kb] = __builtin_amdgcn_mfma_f32_16x16x32_bf16(k1, qf[1], s[kb], 0, 0, 0);
        }

        // ---- online softmax, lane-local over 16 keys + 2 xor-shfls ----
        float mx = s[0][0];
#pragma unroll
        for (int kb = 0; kb < 4; ++kb)
#pragma unroll
            for (int r = 0; r < 4; ++r) mx = fmaxf(mx, s[kb][r]);
        mx = fmaxf(mx, __shfl_xor(mx, 16));
        mx = fmaxf(mx, __shfl_xor(mx, 32));

        if (!__all(mx <= m1 + 8.0f)) {      // T13 defer-max
            float mnew = fmaxf(m1, mx);
            float alpha = __expf(m1 - mnew);
            m1 = mnew;
            l1 *= alpha;
#pragma unroll
            for (int r = 0; r < 4; ++r) {
                float ar = __shfl(alpha, 4 * lg + r);
#pragma unroll
                for (int db = 0; db < 4; ++db) o_[db][r] *= ar;
            }
        }

        float p[4][4];
        float sum = 0.f;
#pragma unroll
        for (int kb = 0; kb < 4; ++kb)
#pragma unroll
            for (int r = 0; r < 4; ++r) { p[kb][r] = __expf(s[kb][r] - m1); sum += p[kb][r]; }
        sum += __shfl_xor(sum, 16);
        sum += __shfl_xor(sum, 32);
        l1 += sum;

        // ---- P write: row=q=lr, keys kb*16+4lg+0..3 -> one b64 per kb ----
#pragma unroll
        for (int kb = 0; kb < 4; ++kb) {
            uint2 pk;
            pk.x = (unsigned)f2bf(p[kb][0]) | ((unsigned)f2bf(p[kb][1]) << 16);
            pk.y = (unsigned)f2bf(p[kb][2]) | ((unsigned)f2bf(p[kb][3]) << 16);
            int chunk = 2 * kb + (lg >> 1);
            *reinterpret_cast<uint2*>(
                PsB + lr * 128 + ((chunk ^ (lr & 7)) << 4) + (lg & 1) * 8) = pk;
        }

        // ---- O += P V ----
        short8 pf[2];
        {
            pf[0] = *reinterpret_cast<const short8*>(
                PsB + lr * 128 + ((lg ^ (lr & 7)) << 4));
            pf[1] = *reinterpret_cast<const short8*>(
                PsB + lr * 128 + (((4 + lg) ^ (lr & 7)) << 4));
        }
#pragma unroll
        for (int db = 0; db < 4; ++db) {
            int row = db * 16 + lr;
            short8 v0 = *reinterpret_cast<const short8*>(
                VtB + row * 128 + ((lg ^ (row & 7)) << 4));
            short8 v1 = *reinterpret_cast<const short8*>(
                VtB + row * 128 + (((4 + lg) ^ (row & 7)) << 4));
            o_[db] = __builtin_amdgcn_mfma_f32_16x16x32_bf16(pf[0], v0, o_[db], 0, 0, 0);
            o_[db] = __builtin_amdgcn_mfma_f32_16x16x32_bf16(pf[1], v1, o_[db], 0, 0, 0);
        }

        if (kt + 1 < N_ / 64) wstage(cur ^ 1);
        __syncthreads();
    }

    // ---- epilogue ----
    const int b = bh >> 3, h = bh & 7;
    float inv = 1.f / l1;
#pragma unroll
    for (int r = 0; r < 4; ++r) {
        float invr = __shfl(inv, 4 * lg + r);
        int n = qt * 64 + w * 16 + 4 * lg + r;
#pragma unroll
        for (int db = 0; db < 4; ++db) {
            O[((size_t)(b * N_ + n)) * (H_ * DV_) + h * DV_ + db * 16 + lr] =
                f2bf(o_[db][r] * invr);
        }
    }
}

// ---------------------------------------------------------------------------
extern "C" void kernel_launch(void* const* d_in, const int* in_sizes, int n_in,
                              void* d_out, int out_size, void* d_ws, size_t ws_size,
                              hipStream_t stream) {
    const float* x   = (const float*)d_in[0];
    const float* Wq  = (const float*)d_in[1];
    const float* bq  = (const float*)d_in[2];
    const float* Wk  = (const float*)d_in[3];
    const float* bk  = (const float*)d_in[4];
    const float* Wv  = (const float*)d_in[5];
    const float* bv  = (const float*)d_in[6];
    const float* WqL = (const float*)d_in[7];
    const float* bqL = (const float*)d_in[8];
    const float* WkL = (const float*)d_in[9];
    const float* bkL = (const float*)d_in[10];
    const float* WvL = (const float*)d_in[11];
    const float* bvL = (const float*)d_in[12];
    const float* Wo  = (const float*)d_in[13];
    const float* bo  = (const float*)d_in[14];

    ushort* Wt_all = (ushort*)d_ws;                    // [2048][512] bf16 (qkv + o)
    ushort* Wot    = Wt_all + (size_t)3 * DM_ * DM_;
    float*  fb     = (float*)(Wt_all + (size_t)4 * DM_ * DM_); // [1536] f32
    ushort* xbf    = (ushort*)(fb + 3 * DM_);
    ushort* Qd     = xbf + (size_t)BN_ * DM_;
    ushort* Kd     = Qd + (size_t)B_ * H_ * N_ * DK_;
    ushort* Vd     = Kd + (size_t)B_ * H_ * N_ * DK_;
    ushort* Od     = Vd + (size_t)B_ * H_ * N_ * DV_;

    float* out = (float*)d_out;

    fuse_transpose4<<<dim3(8, 16, 4), 256, 0, stream>>>(Wq, WqL, Wk, WkL, Wv, WvL, Wo, Wt_all);
    fuse_bias<<<6, 256, 0, stream>>>(bq, bqL, bk, bkL, bv, bvL, fb);
    xcast<<<1024, 256, 0, stream>>>(x, xbf);

    gemm_bf16<128, 0><<<dim3(32, 12), 256, 0, stream>>>(xbf, Wt_all, fb, Qd, Kd, Vd, nullptr);
    attn_mfma<<<dim3(32, 16), 256, 0, stream>>>(Qd, Kd, Vd, Od);
    gemm_bf16<64, 1><<<dim3(32, 8), 256, 0, stream>>>(Od, Wot, bo, nullptr, nullptr, nullptr, out);
}

// Round 5
// 72.076 us; speedup vs baseline: 6.9160x; 1.1236x over previous
//
#include <hip/hip_runtime.h>
#include <hip/hip_bf16.h>

// Problem constants
#define B_  2
#define N_  2048
#define DM_ 512
#define H_  8
#define DK_ 64
#define DV_ 64
#define BN_ (B_*N_)   // 4096 tokens
#define SPLITS 2

typedef __attribute__((ext_vector_type(8))) short short8;
typedef __attribute__((ext_vector_type(4))) float f32x4;
typedef unsigned short ushort;

// fp32 -> bf16 round-to-nearest-even
static __device__ __forceinline__ ushort f2bf(float x) {
    unsigned int u = __float_as_uint(x);
    unsigned int r = (u + 0x7FFFu + ((u >> 16) & 1u)) >> 16;
    return (ushort)r;
}
static __device__ __forceinline__ float bf2f(ushort u) {
    return __uint_as_float(((unsigned)u) << 16);
}
// 2^x single instruction
static __device__ __forceinline__ float exp2_fast(float x) {
    float r; asm("v_exp_f32 %0, %1" : "=v"(r) : "v"(x)); return r;
}
// pack two f32 -> 2x bf16 in one dword (lo=a, hi=b)
static __device__ __forceinline__ unsigned cvt_pk_bf16(float a, float b) {
    unsigned r; asm("v_cvt_pk_bf16_f32 %0, %1, %2" : "=v"(r) : "v"(a), "v"(b)); return r;
}

#define LOG2E 1.4426950408889634f

// ---------------------------------------------------------------------------
// fuse_transpose4: Wt[z][n][k] = bf16(W_z[k][n] + WL_z[k][n]); z=3 has no lora.
// ---------------------------------------------------------------------------
__global__ __launch_bounds__(256) void fuse_transpose4(
        const float* __restrict__ W0, const float* __restrict__ L0,
        const float* __restrict__ W1, const float* __restrict__ L1,
        const float* __restrict__ W2, const float* __restrict__ L2,
        const float* __restrict__ W3, ushort* __restrict__ WtBase) {
    const int z = blockIdx.z;
    const float* W  = (z == 0) ? W0 : (z == 1) ? W1 : (z == 2) ? W2 : W3;
    const float* WL = (z == 0) ? L0 : (z == 1) ? L1 : (z == 2) ? L2 : nullptr;
    ushort* Wt = WtBase + (size_t)z * DM_ * DM_;

    __shared__ float Ws[32][65];
    const int t  = threadIdx.x;
    const int c0 = blockIdx.x * 64;
    const int k0 = blockIdx.y * 32;
    {
        int r = t >> 4, cq = t & 15;
#pragma unroll
        for (int it = 0; it < 2; ++it) {
            int rr = r + it * 16;
            float4 v = *reinterpret_cast<const float4*>(W + (size_t)(k0 + rr) * DM_ + c0 + cq * 4);
            if (WL) {
                float4 u = *reinterpret_cast<const float4*>(WL + (size_t)(k0 + rr) * DM_ + c0 + cq * 4);
                v.x += u.x; v.y += u.y; v.z += u.z; v.w += u.w;
            }
            Ws[rr][cq * 4 + 0] = v.x; Ws[rr][cq * 4 + 1] = v.y;
            Ws[rr][cq * 4 + 2] = v.z; Ws[rr][cq * 4 + 3] = v.w;
        }
    }
    __syncthreads();
    {
        int cr = t >> 2, kq = t & 3;
        short8 o;
#pragma unroll
        for (int j = 0; j < 8; ++j) o[j] = (short)f2bf(Ws[kq * 8 + j][cr]);
        *reinterpret_cast<short8*>(Wt + (size_t)(c0 + cr) * DM_ + k0 + kq * 8) = o;
    }
}

// ---------------------------------------------------------------------------
__global__ void fuse_bias(const float* __restrict__ bq, const float* __restrict__ bqL,
                          const float* __restrict__ bk, const float* __restrict__ bkL,
                          const float* __restrict__ bv, const float* __restrict__ bvL,
                          float* __restrict__ fb) {
    int idx = blockIdx.x * blockDim.x + threadIdx.x;
    if (idx >= 3 * DM_) return;
    int w = idx >> 9, i = idx & 511;
    const float* a = (w == 0) ? bq : (w == 1) ? bk : bv;
    const float* b = (w == 0) ? bqL : (w == 1) ? bkL : bvL;
    fb[idx] = a[i] + b[i];
}

// ---------------------------------------------------------------------------
__global__ void xcast(const float* __restrict__ x, ushort* __restrict__ xb) {
    size_t idx = (size_t)blockIdx.x * blockDim.x + threadIdx.x;
    float4 v0 = *reinterpret_cast<const float4*>(x + idx * 8);
    float4 v1 = *reinterpret_cast<const float4*>(x + idx * 8 + 4);
    short8 o;
    o[0] = (short)f2bf(v0.x); o[1] = (short)f2bf(v0.y);
    o[2] = (short)f2bf(v0.z); o[3] = (short)f2bf(v0.w);
    o[4] = (short)f2bf(v1.x); o[5] = (short)f2bf(v1.y);
    o[6] = (short)f2bf(v1.z); o[7] = (short)f2bf(v1.w);
    *reinterpret_cast<short8*>(xb + idx * 8) = o;
}

// ---------------------------------------------------------------------------
// gemm_bf16: C[M][Ncols] = A[M][512] @ Bt[Ncols][512]^T + bias
// MODE 0: qkv epilogue (bf16 [B,H,N,64]; Q scaled by 0.125*log2e). MODE 1: f32.
// ---------------------------------------------------------------------------
template<int BN, int MODE>
__global__ __launch_bounds__(256) void gemm_bf16(const ushort* __restrict__ A,
                                                 const ushort* __restrict__ Bt,
                                                 const float* __restrict__ bias,
                                                 ushort* __restrict__ Qd,
                                                 ushort* __restrict__ Kd,
                                                 ushort* __restrict__ Vd,
                                                 float* __restrict__ outF) {
    constexpr int NWC = BN / 64;
    constexpr int NWR = 4 / NWC;
    constexpr int MI  = (128 / NWR) / 16;
    constexpr int NJ  = 4;
    const int rt = blockIdx.x, ct = blockIdx.y;
    __shared__ ushort As[128 * 64];
    __shared__ ushort Bs[BN * 64];
    const int t = threadIdx.x, lane = t & 63, w = t >> 6;
    const int wr = w / NWC, wc = w % NWC;
    const int lg = lane >> 4, lr = lane & 15;
    const int rowbase = wr * (128 / NWR);
    const int colbase = wc * 64;

    f32x4 acc[MI][NJ];
#pragma unroll
    for (int mi = 0; mi < MI; ++mi)
#pragma unroll
        for (int nj = 0; nj < NJ; ++nj) acc[mi][nj] = (f32x4){0.f, 0.f, 0.f, 0.f};

    for (int k0 = 0; k0 < DM_; k0 += 64) {
        __syncthreads();
#pragma unroll
        for (int it = 0; it < 4; ++it) {
            int cid = t + it * 256;
            int r = cid >> 3, cq = cid & 7;
            uint4 vld = *reinterpret_cast<const uint4*>(
                A + ((size_t)(rt * 128 + r)) * DM_ + k0 + cq * 8);
            *reinterpret_cast<uint4*>((char*)As + r * 128 + ((cq ^ (r & 7)) << 4)) = vld;
        }
#pragma unroll
        for (int it = 0; it < BN * 8 / 256; ++it) {
            int cid = t + it * 256;
            int r = cid >> 3, cq = cid & 7;
            uint4 vld = *reinterpret_cast<const uint4*>(
                Bt + ((size_t)(ct * BN + r)) * DM_ + k0 + cq * 8);
            *reinterpret_cast<uint4*>((char*)Bs + r * 128 + ((cq ^ (r & 7)) << 4)) = vld;
        }
        __syncthreads();
#pragma unroll
        for (int kh = 0; kh < 2; ++kh) {
            short8 a[MI], b[NJ];
#pragma unroll
            for (int mi = 0; mi < MI; ++mi) {
                int row = rowbase + mi * 16 + lr;
                a[mi] = *reinterpret_cast<const short8*>(
                    (char*)As + row * 128 + (((kh * 4 + lg) ^ (row & 7)) << 4));
            }
#pragma unroll
            for (int nj = 0; nj < NJ; ++nj) {
                int row = colbase + nj * 16 + lr;
                b[nj] = *reinterpret_cast<const short8*>(
                    (char*)Bs + row * 128 + (((kh * 4 + lg) ^ (row & 7)) << 4));
            }
#pragma unroll
            for (int mi = 0; mi < MI; ++mi)
#pragma unroll
                for (int nj = 0; nj < NJ; ++nj)
                    acc[mi][nj] = __builtin_amdgcn_mfma_f32_16x16x32_bf16(
                        a[mi], b[nj], acc[mi][nj], 0, 0, 0);
        }
    }

#pragma unroll
    for (int mi = 0; mi < MI; ++mi) {
#pragma unroll
        for (int nj = 0; nj < NJ; ++nj) {
#pragma unroll
            for (int r = 0; r < 4; ++r) {
                int m = rt * 128 + rowbase + mi * 16 + 4 * lg + r;
                int n = ct * BN + colbase + nj * 16 + lr;
                float v = acc[mi][nj][r] + bias[n];
                if (MODE == 0) {
                    int ws_ = n >> 9;
                    if (ws_ == 0) v *= 0.125f * LOG2E;   // fold softmax scale+log2e into Q
                    ushort* op = (ws_ == 0) ? Qd : (ws_ == 1) ? Kd : Vd;
                    int hd = (n >> 6) & 7, d = n & 63;
                    int bb = m >> 11, nn = m & (N_ - 1);
                    op[(((size_t)(bb * H_ + hd)) * N_ + nn) * DK_ + d] = f2bf(v);
                } else {
                    outF[(size_t)m * DM_ + n] = v;
                }
            }
        }
    }
}

// ---------------------------------------------------------------------------
// vtrans: Vt[bh][d][n] = Vd[bh][n][d].  64x64 tiles, 3-term XOR swizzle.
// grid (N/64, B*H), 256 threads.
// ---------------------------------------------------------------------------
__global__ __launch_bounds__(256) void vtrans(const ushort* __restrict__ Vd,
                                              ushort* __restrict__ Vt) {
    const int bh = blockIdx.y, nt = blockIdx.x;
    __shared__ ushort Ls[64 * 64];
    char* LB = (char*)Ls;
    const int t = threadIdx.x;
#pragma unroll
    for (int i = 0; i < 2; ++i) {
        int c = t + i * 256;
        int tok = c >> 3, dc = c & 7;
        uint4 v = *reinterpret_cast<const uint4*>(
            Vd + ((size_t)bh * N_ + nt * 64 + tok) * DV_ + dc * 8);
        int sw = dc ^ (tok & 7) ^ ((tok >> 3) & 7);
        *reinterpret_cast<uint4*>(LB + tok * 128 + (sw << 4)) = v;
    }
    __syncthreads();
#pragma unroll
    for (int i = 0; i < 2; ++i) {
        int c = t + i * 256;
        int d = c >> 3, tc = c & 7;
        short8 g;
#pragma unroll
        for (int j = 0; j < 8; ++j) {
            int tok = tc * 8 + j;
            int sw = (d >> 3) ^ (tok & 7) ^ ((tok >> 3) & 7);
            g[j] = *reinterpret_cast<const ushort*>(LB + tok * 128 + (sw << 4) + (d & 7) * 2);
        }
        *reinterpret_cast<short8*>(Vt + ((size_t)bh * DV_ + d) * N_ + nt * 64 + tc * 8) = g;
    }
}

// ---------------------------------------------------------------------------
// attn: flash attention, swapped QK^T, exp2 softmax, KV-split x2.
// grid (N/128, B*H, 2), 512 threads (8 waves x 16 q-rows).
// Writes unnormalized partial O (bf16) + (m,l) float2 per row.
// ---------------------------------------------------------------------------
__global__ __launch_bounds__(512) void attn_mfma(const ushort* __restrict__ Q,
                                                 const ushort* __restrict__ K,
                                                 const ushort* __restrict__ Vt,
                                                 ushort* __restrict__ Opart,
                                                 float2* __restrict__ Ml) {
    const int bh = blockIdx.y;
    const int qt = blockIdx.x;
    const int sp = blockIdx.z;
    const int t  = threadIdx.x;
    const int lane = t & 63;
    const int w  = t >> 6;         // 0..7
    const int lg = lane >> 4;
    const int lr = lane & 15;

    __shared__ ushort KsBuf[2][64 * 64];
    __shared__ ushort VtBuf[2][64 * 64];
    __shared__ ushort Ps[8][16 * 64];
    char* PsB = (char*)(Ps[w]);

    const ushort* Kb  = K  + ((size_t)bh * N_ + sp * (N_ / 2)) * DK_;
    const ushort* Vtb = Vt + (size_t)bh * DV_ * N_ + sp * (N_ / 2);

    // staging map: 512 16B-chunks per tile, one per thread
    const int srow = t >> 3, sc = t & 7;

    short8 qf[2];
    {
        const ushort* qrow = Q + ((size_t)bh * N_ + qt * 128 + w * 16 + lr) * DK_;
        qf[0] = *reinterpret_cast<const short8*>(qrow + 8 * lg);
        qf[1] = *reinterpret_cast<const short8*>(qrow + 32 + 8 * lg);
    }

    f32x4 o_[4];
#pragma unroll
    for (int i = 0; i < 4; i++) o_[i] = (f32x4){0.f, 0.f, 0.f, 0.f};
    float m1 = -1e30f, l1 = 0.f;

    uint4 kreg, vreg;
    auto issue = [&](int kt_) {
        kreg = *reinterpret_cast<const uint4*>(Kb  + ((size_t)(kt_ * 64 + srow)) * DK_ + sc * 8);
        vreg = *reinterpret_cast<const uint4*>(Vtb + (size_t)srow * N_ + kt_ * 64 + sc * 8);
    };
    auto wstage = [&](int buf_) {
        *reinterpret_cast<uint4*>((char*)(KsBuf[buf_]) + srow * 128 + ((sc ^ (srow & 7)) << 4)) = kreg;
        *reinterpret_cast<uint4*>((char*)(VtBuf[buf_]) + srow * 128 + ((sc ^ (srow & 7)) << 4)) = vreg;
    };

    issue(0);
    wstage(0);
    __syncthreads();

    const int NT = (N_ / 2) / 64;   // 16 tiles per split
    for (int kt = 0; kt < NT; ++kt) {
        const int cur = kt & 1;
        if (kt + 1 < NT) issue(kt + 1);

        char* KsB = (char*)(KsBuf[cur]);
        char* VtB = (char*)(VtBuf[cur]);

        // ---- S^T = K Q^T : lane holds S[key=kb*16+4lg+r][q=lr], log2 units ----
        f32x4 s[4];
#pragma unroll
        for (int kb = 0; kb < 4; ++kb) {
            int row = kb * 16 + lr;
            short8 k0 = *reinterpret_cast<const short8*>(
                KsB + row * 128 + ((lg ^ (row & 7)) << 4));
            short8 k1 = *reinterpret_cast<const short8*>(
                KsB + row * 128 + (((4 + lg) ^ (row & 7)) << 4));
            f32x4 z = (f32x4){0.f, 0.f, 0.f, 0.f};
            s[kb] = __builtin_amdgcn_mfma_f32_16x16x32_bf16(k0, qf[0], z, 0, 0, 0);
            s[kb] = __builtin_amdgcn_mfma_f32_16x16x32_bf16(k1, qf[1], s[kb], 0, 0, 0);
        }

        // ---- online softmax (base 2), lane-local + 2 xor-shfls ----
        float mx = s[0][0];
#pragma unroll
        for (int kb = 0; kb < 4; ++kb)
#pragma unroll
            for (int r = 0; r < 4; ++r) mx = fmaxf(mx, s[kb][r]);
        mx = fmaxf(mx, __shfl_xor(mx, 16));
        mx = fmaxf(mx, __shfl_xor(mx, 32));

        if (!__all(mx <= m1 + 8.0f)) {      // defer-max (bound p <= 2^8)
            float mnew = fmaxf(m1, mx);
            float alpha = exp2_fast(m1 - mnew);
            m1 = mnew;
            l1 *= alpha;
#pragma unroll
            for (int r = 0; r < 4; ++r) {
                float ar = __shfl(alpha, 4 * lg + r);
#pragma unroll
                for (int db = 0; db < 4; ++db) o_[db][r] *= ar;
            }
        }

        float p[4][4];
        float sum = 0.f;
#pragma unroll
        for (int kb = 0; kb < 4; ++kb)
#pragma unroll
            for (int r = 0; r < 4; ++r) { p[kb][r] = exp2_fast(s[kb][r] - m1); sum += p[kb][r]; }
        sum += __shfl_xor(sum, 16);
        sum += __shfl_xor(sum, 32);
        l1 += sum;

        // ---- P write: one b64 per kb via cvt_pk ----
#pragma unroll
        for (int kb = 0; kb < 4; ++kb) {
            uint2 pk;
            pk.x = cvt_pk_bf16(p[kb][0], p[kb][1]);
            pk.y = cvt_pk_bf16(p[kb][2], p[kb][3]);
            int chunk = 2 * kb + (lg >> 1);
            *reinterpret_cast<uint2*>(
                PsB + lr * 128 + ((chunk ^ (lr & 7)) << 4) + (lg & 1) * 8) = pk;
        }

        // ---- O += P V ----
        short8 pf[2];
        {
            pf[0] = *reinterpret_cast<const short8*>(
                PsB + lr * 128 + ((lg ^ (lr & 7)) << 4));
            pf[1] = *reinterpret_cast<const short8*>(
                PsB + lr * 128 + (((4 + lg) ^ (lr & 7)) << 4));
        }
#pragma unroll
        for (int db = 0; db < 4; ++db) {
            int row = db * 16 + lr;
            short8 v0 = *reinterpret_cast<const short8*>(
                VtB + row * 128 + ((lg ^ (row & 7)) << 4));
            short8 v1 = *reinterpret_cast<const short8*>(
                VtB + row * 128 + (((4 + lg) ^ (row & 7)) << 4));
            o_[db] = __builtin_amdgcn_mfma_f32_16x16x32_bf16(pf[0], v0, o_[db], 0, 0, 0);
            o_[db] = __builtin_amdgcn_mfma_f32_16x16x32_bf16(pf[1], v1, o_[db], 0, 0, 0);
        }

        if (kt + 1 < NT) wstage(cur ^ 1);
        __syncthreads();
    }

    // ---- epilogue: write unnormalized partial O (bf16) + (m,l) ----
    const size_t rowbase = ((size_t)(sp * 16 + bh)) * N_ + qt * 128 + w * 16;
#pragma unroll
    for (int r = 0; r < 4; ++r) {
        int n_loc = 4 * lg + r;
#pragma unroll
        for (int db = 0; db < 4; ++db) {
            Opart[(rowbase + n_loc) * DV_ + db * 16 + lr] = f2bf(o_[db][r]);
        }
    }
    if (lg == 0) {
        Ml[rowbase + lr] = make_float2(m1, l1);
    }
}

// ---------------------------------------------------------------------------
// merge: combine 2 kv-split partials -> final attn output bf16 [B,N,H*DV]
// thread handles 4 dv of one row. grid = B*H*N*16/256.
// ---------------------------------------------------------------------------
__global__ __launch_bounds__(256) void merge_splits(const ushort* __restrict__ Opart,
                                                    const float2* __restrict__ Ml,
                                                    ushort* __restrict__ Od) {
    int gid = blockIdx.x * 256 + threadIdx.x;
    int row = gid >> 4;               // [0, 32768) = bh*2048 + n
    int dv  = (gid & 15) * 4;
    const int R = 16 * N_;            // rows per split
    float2 ml0 = Ml[row];
    float2 ml1 = Ml[R + row];
    float M  = fmaxf(ml0.x, ml1.x);
    float w0 = exp2_fast(ml0.x - M);
    float w1 = exp2_fast(ml1.x - M);
    float inv = 1.f / (w0 * ml0.y + w1 * ml1.y);
    uint2 a = *reinterpret_cast<const uint2*>(Opart + (size_t)row * DV_ + dv);
    uint2 b = *reinterpret_cast<const uint2*>(Opart + ((size_t)R + row) * DV_ + dv);
    const ushort* ae = reinterpret_cast<const ushort*>(&a);
    const ushort* be = reinterpret_cast<const ushort*>(&b);
    uint2 o;
    unsigned* oe = reinterpret_cast<unsigned*>(&o);
#pragma unroll
    for (int half = 0; half < 2; ++half) {
        float v0 = (w0 * bf2f(ae[half * 2 + 0]) + w1 * bf2f(be[half * 2 + 0])) * inv;
        float v1 = (w0 * bf2f(ae[half * 2 + 1]) + w1 * bf2f(be[half * 2 + 1])) * inv;
        oe[half] = cvt_pk_bf16(v0, v1);
    }
    int bh = row >> 11, n = row & (N_ - 1);
    int bb = bh >> 3, h = bh & 7;
    *reinterpret_cast<uint2*>(Od + ((size_t)(bb * N_ + n)) * (H_ * DV_) + h * DV_ + dv) = o;
}

// ---------------------------------------------------------------------------
extern "C" void kernel_launch(void* const* d_in, const int* in_sizes, int n_in,
                              void* d_out, int out_size, void* d_ws, size_t ws_size,
                              hipStream_t stream) {
    const float* x   = (const float*)d_in[0];
    const float* Wq  = (const float*)d_in[1];
    const float* bq  = (const float*)d_in[2];
    const float* Wk  = (const float*)d_in[3];
    const float* bk  = (const float*)d_in[4];
    const float* Wv  = (const float*)d_in[5];
    const float* bv  = (const float*)d_in[6];
    const float* WqL = (const float*)d_in[7];
    const float* bqL = (const float*)d_in[8];
    const float* WkL = (const float*)d_in[9];
    const float* bkL = (const float*)d_in[10];
    const float* WvL = (const float*)d_in[11];
    const float* bvL = (const float*)d_in[12];
    const float* Wo  = (const float*)d_in[13];
    const float* bo  = (const float*)d_in[14];

    ushort* Wt_all = (ushort*)d_ws;                          // [2048][512] bf16
    ushort* Wot    = Wt_all + (size_t)3 * DM_ * DM_;
    float*  fb     = (float*)(Wt_all + (size_t)4 * DM_ * DM_); // [1536] f32
    ushort* xbf    = (ushort*)(fb + 3 * DM_);                // [4096][512]
    ushort* Qd     = xbf + (size_t)BN_ * DM_;
    ushort* Kd     = Qd + (size_t)B_ * H_ * N_ * DK_;
    ushort* Vd     = Kd + (size_t)B_ * H_ * N_ * DK_;
    ushort* Vtd    = Vd + (size_t)B_ * H_ * N_ * DV_;        // [B,H,DV,N]
    ushort* Od     = Vtd + (size_t)B_ * H_ * N_ * DV_;       // [B,N,H*DV]
    ushort* Opart  = Od + (size_t)B_ * H_ * N_ * DV_;        // [2][B*H,N,DV]
    float2* Ml     = (float2*)(Opart + (size_t)SPLITS * B_ * H_ * N_ * DV_);

    float* out = (float*)d_out;

    fuse_transpose4<<<dim3(8, 16, 4), 256, 0, stream>>>(Wq, WqL, Wk, WkL, Wv, WvL, Wo, Wt_all);
    fuse_bias<<<6, 256, 0, stream>>>(bq, bqL, bk, bkL, bv, bvL, fb);
    xcast<<<1024, 256, 0, stream>>>(x, xbf);

    gemm_bf16<128, 0><<<dim3(32, 12), 256, 0, stream>>>(xbf, Wt_all, fb, Qd, Kd, Vd, nullptr);
    vtrans<<<dim3(32, 16), 256, 0, stream>>>(Vd, Vtd);
    attn_mfma<<<dim3(16, 16, SPLITS), 512, 0, stream>>>(Qd, Kd, Vtd, Opart, Ml);
    merge_splits<<<(B_ * H_ * N_ * 16) / 256, 256, 0, stream>>>(Opart, Ml, Od);
    gemm_bf16<64, 1><<<dim3(32, 8), 256, 0, stream>>>(Od, Wot, bo, nullptr, nullptr, nullptr, out);
}